// Round 1
// baseline (3254.953 us; speedup 1.0000x reference)
//
#include <hip/hip_runtime.h>
#include <math.h>

#define Bn 32
#define Tn 64
#define Fdim 32
#define Gdim 32
#define Hdim 256
#define Ndim 20000
#define Cdim 32
#define G4 1024      // 4*H
#define BT 2048      // B*T
#define EPSc 1e-5f

__device__ __forceinline__ float sigmoidf_(float x){ return 1.0f/(1.0f + __expf(-x)); }
__device__ __forceinline__ float tanhf_(float x){ return 2.0f/(1.0f+__expf(-2.0f*x)) - 1.0f; }

// ---- init workspace stats + lookup table -------------------------------
__global__ void init_kernel(float* ws){
  int i = blockIdx.x*256 + threadIdx.x;
  if (i < 2112) ws[i] = 0.0f;                  // gat stats (64) + bn stats (4*512)
  int* table = (int*)(ws + 2112);
  if (i < 40000) table[i] = 0x7fffffff;
}

// ---- gat_output mean/var reduction -------------------------------------
__global__ void bn_stats_kernel(const float* __restrict__ gat, float* __restrict__ sums){
  __shared__ float ss[256], sq[256];
  int tid = threadIdx.x;
  int idx = blockIdx.x*256 + tid;
  int stride = gridDim.x*256;
  const int total = Bn*Ndim*Gdim; // 20,480,000
  float s=0.f,q=0.f;
  for (int i=idx; i<total; i+=stride){ float v = gat[i]; s+=v; q+=v*v; }
  ss[tid]=s; sq[tid]=q; __syncthreads();
  for (int off=128; off>=32; off>>=1){
    if(tid<off){ ss[tid]+=ss[tid+off]; sq[tid]+=sq[tid+off]; }
    __syncthreads();
  }
  if (tid<32){ atomicAdd(&sums[tid], ss[tid]); atomicAdd(&sums[32+tid], sq[tid]); }
}

// ---- node id -> first index table --------------------------------------
__global__ void table_kernel(const int* __restrict__ node_ids, int* __restrict__ table){
  int i = blockIdx.x*256 + threadIdx.x;
  if (i < Ndim) atomicMin(&table[node_ids[i]], i);
}

// ---- gather + normalize + concat -> lstm_in (BT,64) --------------------
__global__ void build_input_kernel(const float* __restrict__ feats, const float* __restrict__ gat,
    const int* __restrict__ row_ids, const int* __restrict__ table, const float* __restrict__ sums,
    const float* __restrict__ bng, const float* __restrict__ bnb, float* __restrict__ out){
  int gt = blockIdx.x*256 + threadIdx.x;     // BT*64 total
  int pos = gt >> 6; int lane = gt & 63;
  float v;
  if (lane < 32){
    v = feats[pos*Fdim + lane];
  } else {
    int g = lane - 32;
    int r = row_ids[pos];
    int idx = table[r];
    if (idx < Ndim){
      int b = pos / Tn;
      float x = gat[(b*Ndim + idx)*Gdim + g];
      const float cnt = (float)(Bn*Ndim);
      float mean = sums[g]/cnt;
      float var  = sums[32+g]/cnt - mean*mean;
      v = (x-mean)*bng[g]*rsqrtf(var+EPSc) + bnb[g];
    } else v = 0.0f;
  }
  out[gt] = v;
}

// ---- transpose all weight matrices (1024,K) -> (K,1024) ----------------
struct TArgs { const float* src[16]; float* dst[16]; int K[16]; };
__global__ void transpose_kernel(TArgs a){
  __shared__ float tile[32][33];
  int mat = blockIdx.y;
  int K = a.K[mat];
  int tc = blockIdx.x & 7; int tr = blockIdx.x >> 3;   // gridDim.x = 256
  if (tc*32 >= K) return;
  const float* src = a.src[mat]; float* dst = a.dst[mat];
  int tx = threadIdx.x; int ty = threadIdx.y;          // 32 x 8
  int r0 = tr*32, c0 = tc*32;
  #pragma unroll
  for (int i=0;i<4;i++){ int r = ty + i*8; tile[r][tx] = src[(r0+r)*K + c0+tx]; }
  __syncthreads();
  #pragma unroll
  for (int i=0;i<4;i++){ int r = ty + i*8; dst[(c0 + r)*G4 + r0 + tx] = tile[tx][r]; }
}

// ---- input projection: out(m,1024) = x(m,K) @ WT(K,1024) + bias --------
struct PArgs { const float* x[3]; const float* wt[3]; const float* bias[3]; float* out[3]; int K; };
__global__ __launch_bounds__(256) void proj_kernel(PArgs a){
  int hd = blockIdx.z;
  int j  = blockIdx.y*256 + threadIdx.x;
  int m0 = blockIdx.x*4;
  const float* x  = a.x[hd];
  const float* wt = a.wt[hd];
  int K = a.K;
  float bv = a.bias[hd][j];
  float acc0=bv, acc1=bv, acc2=bv, acc3=bv;
  const float* x0 = x + m0*K;   // uniform addresses -> scalar loads
  #pragma unroll 4
  for (int k=0;k<K;k++){
    float w = wt[k*G4 + j];
    acc0 = fmaf(x0[k],     w, acc0);
    acc1 = fmaf(x0[K+k],   w, acc1);
    acc2 = fmaf(x0[2*K+k], w, acc2);
    acc3 = fmaf(x0[3*K+k], w, acc3);
  }
  float* out = a.out[hd] + m0*G4 + j;
  out[0]=acc0; out[G4]=acc1; out[2*G4]=acc2; out[3*G4]=acc3;
}

// ---- LSTM recurrence: one block per (batch, head) ----------------------
struct RArgs { const float* xp[3]; const float* wt[3]; float* out[3]; };
__global__ __launch_bounds__(256) void rec_kernel(RArgs a){
  int b = blockIdx.x; int hd = blockIdx.y; int tid = threadIdx.x;
  const float* xp = a.xp[hd] + b*Tn*G4;
  const float4* wp = (const float4*)a.wt[hd] + tid;   // + k*256 per k-row
  float* out = a.out[hd] + b*Tn*Hdim;
  __shared__ float hbuf[2][Hdim];
  __shared__ float gbuf[G4];
  float c = 0.0f;
  hbuf[0][tid] = 0.0f;
  __syncthreads();
  int p = 0;
  for (int t=0;t<Tn;t++){
    float4 acc = *(const float4*)(xp + t*G4 + 4*tid);
    const float* hrow = hbuf[p];
    #pragma unroll 4
    for (int k=0;k<Hdim;k++){
      float hk = hrow[k];
      float4 w = wp[k*(G4/4)];
      acc.x = fmaf(w.x,hk,acc.x); acc.y = fmaf(w.y,hk,acc.y);
      acc.z = fmaf(w.z,hk,acc.z); acc.w = fmaf(w.w,hk,acc.w);
    }
    ((float4*)gbuf)[tid] = acc;
    __syncthreads();
    float gi = gbuf[tid], gf = gbuf[Hdim+tid], gg = gbuf[2*Hdim+tid], go = gbuf[3*Hdim+tid];
    c = sigmoidf_(gf)*c + sigmoidf_(gi)*tanhf_(gg);
    float h = sigmoidf_(go)*tanhf_(c);
    out[t*Hdim + tid] = h;
    hbuf[p^1][tid] = h;
    __syncthreads();
    p ^= 1;
  }
}

// ---- per-feature mean/var stats over (B,T) -----------------------------
struct SArgs { const float* in[3]; float* stats[3]; };
__global__ void stats_kernel(SArgs a){
  int hd = blockIdx.y; int tid = threadIdx.x;
  const float* in = a.in[hd] + blockIdx.x*256*Hdim;
  float s=0.f,q=0.f;
  for (int r=0;r<256;r++){ float v = in[r*Hdim + tid]; s+=v; q+=v*v; }
  atomicAdd(&a.stats[hd][tid], s);
  atomicAdd(&a.stats[hd][Hdim+tid], q);
}

// ---- normalize shared output ------------------------------------------
__global__ void norm_kernel(const float* __restrict__ in, const float* __restrict__ stats,
   const float* __restrict__ g, const float* __restrict__ bta, float* __restrict__ out){
  int i = blockIdx.x*256 + threadIdx.x;
  int h = i & 255;
  float mean = stats[h]*(1.0f/BT);
  float var  = stats[Hdim+h]*(1.0f/BT) - mean*mean;
  out[i] = (in[i]-mean)*g[h]*rsqrtf(var+EPSc) + bta[h];
}

// ---- final: normalize last step of heads, fc + softmax -----------------
__global__ __launch_bounds__(256) void final_kernel(
  const float* __restrict__ h0, const float* __restrict__ h1, const float* __restrict__ h2,
  const float* __restrict__ stats,    // base ws+S_BN; head hd at (1+hd)*512
  const float* __restrict__ hbg, const float* __restrict__ hbb,
  const float* __restrict__ actW, const float* __restrict__ actB,
  const float* __restrict__ tW, const float* __restrict__ tB,
  const float* __restrict__ rW, const float* __restrict__ rB,
  float* __restrict__ outp){
  __shared__ float v0[Bn*Hdim];
  __shared__ float lg[Bn*Cdim];
  int tid = threadIdx.x;
  for (int i=tid; i<Bn*Hdim; i+=256){
    int b=i>>8, h=i&255;
    float sm = stats[512 + h], sq = stats[512+256+h];
    float mean = sm*(1.0f/BT); float var = sq*(1.0f/BT) - mean*mean;
    v0[i] = (h0[(b*Tn+63)*Hdim + h] - mean)*hbg[h]*rsqrtf(var+EPSc) + hbb[h];
  }
  __syncthreads();
  for (int i=tid; i<Bn*Cdim; i+=256){
    int b=i>>5, cc=i&31;
    float acc = actB[cc];
    const float* wrow = actW + cc*Hdim;
    const float* vrow = v0 + b*Hdim;
    #pragma unroll 4
    for (int h=0;h<Hdim;h++) acc = fmaf(vrow[h], wrow[h], acc);
    lg[i] = acc;
  }
  __syncthreads();
  if (tid < Bn){
    int b = tid;
    float m = -1e30f;
    #pragma unroll
    for (int cc=0; cc<Cdim; cc++) m = fmaxf(m, lg[b*Cdim+cc]);
    float e[Cdim]; float s = 0.f;
    #pragma unroll
    for (int cc=0; cc<Cdim; cc++){ float ee = __expf(lg[b*Cdim+cc]-m); e[cc]=ee; s+=ee; }
    float inv = 1.0f/s;
    #pragma unroll
    for (int cc=0; cc<Cdim; cc++) outp[b*Cdim+cc] = e[cc]*inv;
  }
  if (tid < 64){
    int b = tid & 31; int w = tid >> 5;
    const float* hh = w ? h2 : h1;
    const float* fw = w ? rW : tW;
    float fb = w ? rB[0] : tB[0];
    int hd = 1 + w;
    float acc = fb;
    for (int h=0; h<Hdim; h++){
      float sm = stats[(1+hd)*512 + h], sq = stats[(1+hd)*512+256+h];
      float mean = sm*(1.0f/BT); float var = sq*(1.0f/BT) - mean*mean;
      float v = (hh[(b*Tn+63)*Hdim + h] - mean)*hbg[hd*Hdim+h]*rsqrtf(var+EPSc) + hbb[hd*Hdim+h];
      acc = fmaf(v, fw[h], acc);
    }
    outp[1024 + w*32 + b] = acc;
  }
}

extern "C" void kernel_launch(void* const* d_in, const int* in_sizes, int n_in,
                              void* d_out, int out_size, void* d_ws, size_t ws_size,
                              hipStream_t stream){
  const float* data_feats = (const float*)d_in[0];
  const float* gat   = (const float*)d_in[1];
  const int*   row_ids  = (const int*)d_in[2];
  const int*   node_ids = (const int*)d_in[3];
  const float* sWih0 = (const float*)d_in[4];
  const float* sWhh0 = (const float*)d_in[5];
  const float* sb0   = (const float*)d_in[6];
  const float* sWih1 = (const float*)d_in[7];
  const float* sWhh1 = (const float*)d_in[8];
  const float* sb1   = (const float*)d_in[9];
  const float* hWih  = (const float*)d_in[10];
  const float* hWhh  = (const float*)d_in[11];
  const float* hb    = (const float*)d_in[12];
  const float* bng   = (const float*)d_in[13];
  const float* bnb   = (const float*)d_in[14];
  const float* bsg   = (const float*)d_in[15];
  const float* bsb   = (const float*)d_in[16];
  const float* hbg   = (const float*)d_in[17];
  const float* hbb   = (const float*)d_in[18];
  const float* actW  = (const float*)d_in[19];
  const float* actB  = (const float*)d_in[20];
  const float* tW    = (const float*)d_in[21];
  const float* tB    = (const float*)d_in[22];
  const float* rW    = (const float*)d_in[23];
  const float* rB    = (const float*)d_in[24];
  float* ws  = (float*)d_ws;
  float* out = (float*)d_out;

  // workspace layout (float offsets)
  const size_t S_GAT = 0;                       // 64
  const size_t S_BN  = 64;                      // 4*512
  const size_t TABLE = 2112;                    // 40000 ints
  const size_t TWOFF = 42112;                   // 16 slots x 262144
  const size_t SLOT  = 262144;
  const size_t LSTM_IN = TWOFF + 16*SLOT;       // 4,236,416
  const size_t XPOFF   = LSTM_IN + 131072;      // 3 x 2,097,152
  const size_t BUF0 = XPOFF + 3*2097152;
  const size_t BUF1 = BUF0 + 524288;
  const size_t BUFN = BUF1 + 524288;
  const size_t HB0  = BUFN + 524288;
  const size_t HB1  = HB0 + 3*524288;           // end = HB1 + 3*524288 = 15,377,536 floats

  init_kernel<<<157,256,0,stream>>>(ws);
  bn_stats_kernel<<<2048,256,0,stream>>>(gat, ws+S_GAT);
  table_kernel<<<(Ndim+255)/256,256,0,stream>>>(node_ids, (int*)(ws+TABLE));
  build_input_kernel<<<512,256,0,stream>>>(data_feats, gat, row_ids, (int*)(ws+TABLE),
                                           ws+S_GAT, bng, bnb, ws+LSTM_IN);

  TArgs ta;
  float* tw = ws + TWOFF;
  ta.src[0]=sWih0; ta.K[0]=64;
  ta.src[1]=sWhh0; ta.K[1]=256;
  ta.src[2]=sWih1; ta.K[2]=256;
  ta.src[3]=sWhh1; ta.K[3]=256;
  for (int hd=0; hd<3; hd++) for (int l=0;l<2;l++){
    ta.src[4+hd*2+l]  = hWih + (size_t)(hd*2+l)*G4*Hdim; ta.K[4+hd*2+l]  = 256;
    ta.src[10+hd*2+l] = hWhh + (size_t)(hd*2+l)*G4*Hdim; ta.K[10+hd*2+l] = 256;
  }
  for (int i=0;i<16;i++) ta.dst[i] = tw + i*SLOT;
  transpose_kernel<<<dim3(256,16),dim3(32,8),0,stream>>>(ta);

  PArgs pa; RArgs ra; SArgs sa;
  // shared layer 0
  pa.K=64; pa.x[0]=ws+LSTM_IN; pa.wt[0]=tw+0*SLOT; pa.bias[0]=sb0; pa.out[0]=ws+XPOFF;
  proj_kernel<<<dim3(512,4,1),256,0,stream>>>(pa);
  ra.xp[0]=ws+XPOFF; ra.wt[0]=tw+1*SLOT; ra.out[0]=ws+BUF0;
  rec_kernel<<<dim3(32,1),256,0,stream>>>(ra);
  // shared layer 1
  pa.K=256; pa.x[0]=ws+BUF0; pa.wt[0]=tw+2*SLOT; pa.bias[0]=sb1; pa.out[0]=ws+XPOFF;
  proj_kernel<<<dim3(512,4,1),256,0,stream>>>(pa);
  ra.xp[0]=ws+XPOFF; ra.wt[0]=tw+3*SLOT; ra.out[0]=ws+BUF1;
  rec_kernel<<<dim3(32,1),256,0,stream>>>(ra);
  // shared batchnorm
  sa.in[0]=ws+BUF1; sa.stats[0]=ws+S_BN;
  stats_kernel<<<dim3(8,1),256,0,stream>>>(sa);
  norm_kernel<<<2048,256,0,stream>>>(ws+BUF1, ws+S_BN, bsg, bsb, ws+BUFN);
  // heads layer 0
  pa.K=256;
  for (int hd=0;hd<3;hd++){
    pa.x[hd]=ws+BUFN; pa.wt[hd]=tw+(4+hd*2)*SLOT; pa.bias[hd]=hb + (size_t)(hd*2)*G4;
    pa.out[hd]=ws+XPOFF+(size_t)hd*2097152;
  }
  proj_kernel<<<dim3(512,4,3),256,0,stream>>>(pa);
  for (int hd=0;hd<3;hd++){
    ra.xp[hd]=ws+XPOFF+(size_t)hd*2097152; ra.wt[hd]=tw+(10+hd*2)*SLOT; ra.out[hd]=ws+HB0+(size_t)hd*524288;
  }
  rec_kernel<<<dim3(32,3),256,0,stream>>>(ra);
  // heads layer 1
  for (int hd=0;hd<3;hd++){
    pa.x[hd]=ws+HB0+(size_t)hd*524288; pa.wt[hd]=tw+(4+hd*2+1)*SLOT; pa.bias[hd]=hb + (size_t)(hd*2+1)*G4;
    pa.out[hd]=ws+XPOFF+(size_t)hd*2097152;
  }
  proj_kernel<<<dim3(512,4,3),256,0,stream>>>(pa);
  for (int hd=0;hd<3;hd++){
    ra.xp[hd]=ws+XPOFF+(size_t)hd*2097152; ra.wt[hd]=tw+(10+hd*2+1)*SLOT; ra.out[hd]=ws+HB1+(size_t)hd*524288;
  }
  rec_kernel<<<dim3(32,3),256,0,stream>>>(ra);
  // heads batchnorm stats
  for (int hd=0;hd<3;hd++){ sa.in[hd]=ws+HB1+(size_t)hd*524288; sa.stats[hd]=ws+S_BN+(size_t)(1+hd)*512; }
  stats_kernel<<<dim3(8,3),256,0,stream>>>(sa);
  // final outputs
  final_kernel<<<1,256,0,stream>>>(ws+HB1, ws+HB1+524288, ws+HB1+2*524288, ws+S_BN,
                                   hbg, hbb, actW, actB, tW, tB, rW, rB, out);
}